// Round 15
// baseline (498.220 us; speedup 1.0000x reference)
//
#include <hip/hip_runtime.h>
#include <math.h>

#define HDIM 128
#define BSH 7                 // bucket = dst >> 7 (128 nodes per bucket)
#define MAXBUCK 512

typedef __attribute__((ext_vector_type(8))) short    bf16x8;
typedef __attribute__((ext_vector_type(4))) float    f32x4;
typedef __attribute__((ext_vector_type(2))) float    f32x2;
typedef __attribute__((ext_vector_type(8))) unsigned short u16x8;
typedef __attribute__((ext_vector_type(4))) unsigned short u16x4;

__device__ __forceinline__ float bf2f(unsigned short u) {
    union { unsigned int i; float f; } c; c.i = ((unsigned int)u) << 16; return c.f;
}
__device__ __forceinline__ unsigned short f2bf(float f) {
    union { float f; unsigned int i; } c; c.f = f;
    unsigned int r = (c.i + 0x7fffu + ((c.i >> 16) & 1u)) >> 16;
    return (unsigned short)r;
}
// decode 8 fp8 (e4m3) packed in uint2 -> 8 floats
__device__ __forceinline__ void f8x8_dec(uint2 v, float* f) {
    f32x2 a = __builtin_amdgcn_cvt_pk_f32_fp8((int)v.x, false);
    f32x2 b = __builtin_amdgcn_cvt_pk_f32_fp8((int)v.x, true);
    f32x2 c = __builtin_amdgcn_cvt_pk_f32_fp8((int)v.y, false);
    f32x2 d = __builtin_amdgcn_cvt_pk_f32_fp8((int)v.y, true);
    f[0] = a.x; f[1] = a.y; f[2] = b.x; f[3] = b.y;
    f[4] = c.x; f[5] = c.y; f[6] = d.x; f[7] = d.y;
}

// ---------------- CSR stage 1: per-block bucket histograms ----------------
__global__ __launch_bounds__(256) void k_hist(
    const int* __restrict__ dst, int* __restrict__ tot,
    int* __restrict__ hist, int E, int chunk, int nbuck)
{
    __shared__ int h[MAXBUCK];
    for (int i = threadIdx.x; i < MAXBUCK; i += 256) h[i] = 0;
    __syncthreads();
    int beg = blockIdx.x * chunk;
    int fin = min(beg + chunk, E);
    for (int e = beg + threadIdx.x; e < fin; e += 256)
        atomicAdd(&h[dst[e] >> BSH], 1);
    __syncthreads();
    for (int k = threadIdx.x; k < nbuck; k += 256) {
        int v = h[k];
        hist[(size_t)blockIdx.x * nbuck + k] = v;
        if (v) atomicAdd(&tot[k], v);
    }
}

// ---------------- CSR stage 2: exclusive scan of bucket totals ----------------
__global__ __launch_bounds__(256) void k_scan_buckets(
    const int* __restrict__ tot, int* __restrict__ gcur, int* __restrict__ base, int nbuck)
{
    __shared__ int a[MAXBUCK], b[MAXBUCK];
    int t = threadIdx.x;
    for (int i = t; i < MAXBUCK; i += 256) a[i] = (i < nbuck) ? tot[i] : 0;
    __syncthreads();
    int* s1 = a; int* s2 = b;
    for (int off = 1; off < MAXBUCK; off <<= 1) {
        for (int i = t; i < MAXBUCK; i += 256)
            s2[i] = s1[i] + ((i >= off) ? s1[i - off] : 0);
        __syncthreads();
        int* tmp = s1; s1 = s2; s2 = tmp;
    }
    for (int i = t; i < nbuck; i += 256) {
        int e = (i == 0) ? 0 : s1[i - 1];
        gcur[i] = e;
        base[i] = e;
    }
    if (t == 0) base[nbuck] = s1[nbuck - 1];
}

// ---------------- CSR stage 3: partition edges into bucket segments ----------------
// staging entry: { src | (dst<<16), edge_id }  (N < 65536)
__global__ __launch_bounds__(256) void k_partition(
    const int* __restrict__ src, const int* __restrict__ dst,
    const int* __restrict__ hist, int* __restrict__ gcur,
    uint2* __restrict__ stag, int E, int chunk, int nbuck)
{
    __shared__ int h[MAXBUCK];
    int t = threadIdx.x;
    for (int k = t; k < nbuck; k += 256) {
        int v = hist[(size_t)blockIdx.x * nbuck + k];
        h[k] = v ? atomicAdd(&gcur[k], v) : 0;
    }
    __syncthreads();
    int beg = blockIdx.x * chunk;
    int fin = min(beg + chunk, E);
    for (int e = beg + t; e < fin; e += 256) {
        unsigned int d = (unsigned int)dst[e];
        unsigned int s = (unsigned int)src[e];
        int pos = atomicAdd(&h[d >> BSH], 1);
        stag[pos] = make_uint2(s | (d << 16), (unsigned int)e);
    }
}

// ---------------- CSR stage 4: per-bucket counts + row_ptr + col/epk scatter + dis ----------------
__global__ __launch_bounds__(256) void k_bucket_csr(
    const int* __restrict__ base, const uint2* __restrict__ stag,
    int* __restrict__ row_ptr, int* __restrict__ col, uint2* __restrict__ epk,
    float* __restrict__ dis, int n, int nbuck)
{
    __shared__ int cl[128], sa[128], sb[128], cur[128];
    int k = blockIdx.x;
    int n0 = k << BSH;
    int t = threadIdx.x;
    if (t < 128) cl[t] = 0;
    __syncthreads();
    int b0 = base[k];
    int m = base[k + 1] - b0;
    const uint2* seg = stag + b0;
    for (int i = t; i < m; i += 256) atomicAdd(&cl[(seg[i].x >> 16) & 127], 1);
    __syncthreads();
    int cv = 0;
    if (t < 128) { cv = cl[t]; sa[t] = cv; }
    __syncthreads();
    int* s1 = sa; int* s2 = sb;
    for (int off = 1; off < 128; off <<= 1) {
        if (t < 128) s2[t] = s1[t] + ((t >= off) ? s1[t - off] : 0);
        __syncthreads();
        int* tmp = s1; s1 = s2; s2 = tmp;
    }
    if (t < 128) {
        int node = n0 + t;
        if (node < n) {
            int rpv = b0 + s1[t] - cv;
            row_ptr[node] = rpv;
            cur[t] = rpv;
            dis[node] = rsqrtf(1.0f + (float)cv);
        }
    }
    if (k == 0 && t == 0) row_ptr[n] = base[nbuck];
    __syncthreads();
    for (int i = t; i < m; i += 256) {
        uint2 e = seg[i];
        int pos = atomicAdd(&cur[(e.x >> 16) & 127], 1);
        int s = (int)(e.x & 0xffffu);
        col[pos] = s;
        epk[pos] = make_uint2((unsigned int)s, e.y);
    }
}

// ---------------- weight prep: fp32 W[KxH] -> bf16 W^T[HxK] ----------------
struct WEnt { const float* src; unsigned short* dst; int K; };
struct WAll { WEnt w[7]; };

__global__ __launch_bounds__(256) void k_prep_w(WAll all) {
    WEnt e = all.w[blockIdx.y];
    int i = blockIdx.x * 256 + threadIdx.x;
    if (i >= e.K * HDIM) return;
    int k = i >> 7, c = i & 127;
    e.dst[(size_t)c * e.K + k] = f2bf(e.src[i]);
}

// ---------------- MFMA GEMM (bf16 A), K=128; Wt staged in LDS (fragment order) ----------------
// out_mode: 0 = bf16 full-row, 1 = fp8 full-row (128B), 2 = fp8 feature-split halves (2 x M*64B)
__global__ __launch_bounds__(256) void k_gemm_b(
    const unsigned short* __restrict__ X, const unsigned short* __restrict__ Wt,
    const float* __restrict__ bias, const float* __restrict__ scale,
    void* __restrict__ C, int M, int relu_out, int out_mode)
{
    __shared__ unsigned short sW[128 * 128];   // 32 KB
    const int t = threadIdx.x;
#pragma unroll
    for (int i = 0; i < 8; i++) {
        int c = t + i * 256;                 // 16-B chunk 0..2047 (row-major source)
        int row = c >> 4, o = c & 15;        // row 0..127, o = k-octet 0..15
        int mt = row >> 4, r = row & 15, kc = o >> 2, q = o & 3;
        int lidx = (mt * 4 + kc) * 64 + q * 16 + r;
        *(uint4*)(sW + (size_t)lidx * 8) = *(const uint4*)(Wt + (size_t)c * 8);
    }
    __syncthreads();
    int wave = t >> 6, lane = t & 63;
    int quad = lane >> 4, r = lane & 15;
    int row0 = blockIdx.x * 64 + wave * 16;
    if (row0 >= M) return;                   // M % 16 == 0: whole waves only
    const unsigned short* xp = X + (size_t)(row0 + r) * 128 + quad * 8;
    f32x4 acc[8];
#pragma unroll
    for (int mt = 0; mt < 8; mt++) acc[mt] = (f32x4){0.f, 0.f, 0.f, 0.f};
#pragma unroll
    for (int kc = 0; kc < 4; kc++) {
        bf16x8 xf = *(const bf16x8*)(xp + kc * 32);
#pragma unroll
        for (int mt = 0; mt < 8; mt++) {
            bf16x8 wf = *(const bf16x8*)(sW + ((size_t)((mt * 4 + kc) * 64 + lane)) * 8);
            acc[mt] = __builtin_amdgcn_mfma_f32_16x16x32_bf16(wf, xf, acc[mt], 0, 0, 0);
        }
    }
    float sc = scale ? scale[row0 + r] : 1.f;
    if (out_mode != 0) {
#pragma unroll
        for (int mt = 0; mt < 8; mt++) {
            float v[4];
#pragma unroll
            for (int j = 0; j < 4; j++) {
                float x = acc[mt][j];
                if (bias) x += bias[mt * 16 + quad * 4 + j];
                if (relu_out) x = fmaxf(x, 0.f);
                v[j] = x * sc;
            }
            int wd = 0;
            wd = __builtin_amdgcn_cvt_pk_fp8_f32(v[0], v[1], wd, false);
            wd = __builtin_amdgcn_cvt_pk_fp8_f32(v[2], v[3], wd, true);
            unsigned char* cp;
            if (out_mode == 2) {
                // feature-split: half h = mt>>2, 64B rows per half
                cp = (unsigned char*)C + (size_t)(mt >> 2) * M * 64
                   + (size_t)(row0 + r) * 64 + (mt & 3) * 16 + quad * 4;
            } else {
                cp = (unsigned char*)C + (size_t)(row0 + r) * HDIM + mt * 16 + quad * 4;
            }
            *(unsigned int*)cp = (unsigned int)wd;
        }
    } else {
        unsigned short* cp = (unsigned short*)C + (size_t)(row0 + r) * HDIM + quad * 4;
#pragma unroll
        for (int mt = 0; mt < 8; mt++) {
            u16x4 o;
#pragma unroll
            for (int j = 0; j < 4; j++) {
                float v = acc[mt][j];
                if (bias) v += bias[mt * 16 + quad * 4 + j];
                if (relu_out) v = fmaxf(v, 0.f);
                o[j] = f2bf(v * sc);
            }
            *(u16x4*)(cp + mt * 16) = o;
        }
    }
}

// ---------------- MFMA GEMM (fp32 A = node_features), K=256; Wt staged in LDS ----------------
__global__ __launch_bounds__(256) void k_gemm_nf(
    const float* __restrict__ X, const unsigned short* __restrict__ Wt,
    const float* __restrict__ bias, unsigned short* __restrict__ C,
    int M, int relu_out)
{
    const int K = 256;
    __shared__ unsigned short sW[128 * 256];   // 64 KB
    const int t = threadIdx.x;
#pragma unroll
    for (int i = 0; i < 16; i++) {
        int c = t + i * 256;                 // 16-B chunk 0..4095
        int row = c >> 5, o = c & 31;        // row 0..127, o = k-octet 0..31
        int mt = row >> 4, r = row & 15, kc = o >> 2, q = o & 3;
        int lidx = (mt * 8 + kc) * 64 + q * 16 + r;
        *(uint4*)(sW + (size_t)lidx * 8) = *(const uint4*)(Wt + (size_t)c * 8);
    }
    __syncthreads();
    int wave = t >> 6, lane = t & 63;
    int quad = lane >> 4, r = lane & 15;
    int row0 = blockIdx.x * 64 + wave * 16;
    if (row0 >= M) return;
    const float* xp = X + (size_t)(row0 + r) * K + quad * 8;
    f32x4 acc[8];
#pragma unroll
    for (int mt = 0; mt < 8; mt++) acc[mt] = (f32x4){0.f, 0.f, 0.f, 0.f};
#pragma unroll 2
    for (int kc = 0; kc < 8; kc++) {
        float4 xa = *(const float4*)(xp + kc * 32);
        float4 xb = *(const float4*)(xp + kc * 32 + 4);
        bf16x8 xf;
        xf[0] = (short)f2bf(xa.x); xf[1] = (short)f2bf(xa.y);
        xf[2] = (short)f2bf(xa.z); xf[3] = (short)f2bf(xa.w);
        xf[4] = (short)f2bf(xb.x); xf[5] = (short)f2bf(xb.y);
        xf[6] = (short)f2bf(xb.z); xf[7] = (short)f2bf(xb.w);
#pragma unroll
        for (int mt = 0; mt < 8; mt++) {
            bf16x8 wf = *(const bf16x8*)(sW + ((size_t)((mt * 8 + kc) * 64 + lane)) * 8);
            acc[mt] = __builtin_amdgcn_mfma_f32_16x16x32_bf16(wf, xf, acc[mt], 0, 0, 0);
        }
    }
    unsigned short* cp = C + (size_t)(row0 + r) * HDIM + quad * 4;
#pragma unroll
    for (int mt = 0; mt < 8; mt++) {
        u16x4 o;
#pragma unroll
        for (int j = 0; j < 4; j++) {
            float v = acc[mt][j];
            if (bias) v += bias[mt * 16 + quad * 4 + j];
            if (relu_out) v = fmaxf(v, 0.f);
            o[j] = f2bf(v);
        }
        *(u16x4*)(cp + mt * 16) = o;
    }
}

// ---------------- aggregate over one feature half (3.2MB table -> L2-resident per XCD) ----------------
// y8h: M x 64B fp8 half-table (8 uint2/row). Lane = oct*8 + t: 8 octs process 8 edges
// concurrently, 8 lanes x 8B cover the 64-feature half. acc[8]/lane (VGPR-lean).
__global__ __launch_bounds__(256) void k_aggregate_f8h(
    const int* __restrict__ row_ptr, const int* __restrict__ col,
    const float* __restrict__ dis, const uint2* __restrict__ y8h,
    const float* __restrict__ bias64, unsigned short* __restrict__ out_half,
    int n, int relu_out)
{
    int wid = (blockIdx.x * 256 + threadIdx.x) >> 6;
    if (wid >= n) return;
    int lane = threadIdx.x & 63;
    int oct = lane >> 3, t = lane & 7;
    float acc[8];
    {
        uint2 sv = y8h[(size_t)wid * 8 + t];        // self term
        float f[8]; f8x8_dec(sv, f);
#pragma unroll
        for (int i = 0; i < 8; i++) acc[i] = (oct == 0) ? f[i] : 0.f;
    }
    int beg = row_ptr[wid], end = row_ptr[wid + 1];
    int j = beg + oct;
    // 4-deep x 8 edges/inst = 32 edges in flight per wave
    for (; j + 24 < end; j += 32) {
        int s[4]; uint2 v[4];
#pragma unroll
        for (int u = 0; u < 4; u++) s[u] = col[j + u * 8];
#pragma unroll
        for (int u = 0; u < 4; u++) v[u] = y8h[(size_t)s[u] * 8 + t];
#pragma unroll
        for (int u = 0; u < 4; u++) {
            float f[8]; f8x8_dec(v[u], f);
#pragma unroll
            for (int i = 0; i < 8; i++) acc[i] += f[i];
        }
    }
    for (; j < end; j += 8) {
        int s = col[j];
        uint2 v = y8h[(size_t)s * 8 + t];
        float f[8]; f8x8_dec(v, f);
#pragma unroll
        for (int i = 0; i < 8; i++) acc[i] += f[i];
    }
#pragma unroll
    for (int i = 0; i < 8; i++) {
        acc[i] += __shfl_xor(acc[i], 8, 64);
        acc[i] += __shfl_xor(acc[i], 16, 64);
        acc[i] += __shfl_xor(acc[i], 32, 64);
    }
    if (oct == 0) {
        float di = dis[wid];
        u16x8 o;
#pragma unroll
        for (int i = 0; i < 8; i++) {
            float v = di * acc[i] + bias64[t * 8 + i];
            if (relu_out) v = fmaxf(v, 0.f);
            o[i] = f2bf(v);
        }
        *(u16x8*)(out_half + (size_t)wid * HDIM + t * 8) = o;
    }
}

// ---------------- edge scorer: wave per dst node, Q loaded once, P random, 2-deep ----------------
__global__ __launch_bounds__(256) void k_edge_score_csr(
    const int* __restrict__ row_ptr, const uint2* __restrict__ epk,
    const uint2* __restrict__ P8, const uint2* __restrict__ Q8,
    const float* __restrict__ w2, const float* __restrict__ b2,
    float* __restrict__ out, int n)
{
    int wid = (blockIdx.x * 256 + threadIdx.x) >> 6;
    if (wid >= n) return;
    int lane = threadIdx.x & 63;
    int q = lane >> 4, t = lane & 15;
    float w[8];
#pragma unroll
    for (int j = 0; j < 8; j++) w[j] = w2[t * 8 + j];
    float bb = b2[0];
    float qf[8];
    {
        uint2 qv = Q8[(size_t)wid * 16 + t];  // sequential per node, shared by all 4 quads
        f8x8_dec(qv, qf);
    }
    int beg = row_ptr[wid], end = row_ptr[wid + 1];
    int j = beg + q;
    for (; j + 4 < end; j += 8) {
        uint2 e0 = epk[j], e1 = epk[j + 4];
        uint2 pv0 = P8[(size_t)e0.x * 16 + t];
        uint2 pv1 = P8[(size_t)e1.x * 16 + t];
        float pf0[8], pf1[8];
        f8x8_dec(pv0, pf0); f8x8_dec(pv1, pf1);
        float p0 = 0.f, p1 = 0.f;
#pragma unroll
        for (int i = 0; i < 8; i++) {
            p0 += fmaxf(pf0[i] + qf[i], 0.f) * w[i];
            p1 += fmaxf(pf1[i] + qf[i], 0.f) * w[i];
        }
        p0 += __shfl_xor(p0, 8, 16); p1 += __shfl_xor(p1, 8, 16);
        p0 += __shfl_xor(p0, 4, 16); p1 += __shfl_xor(p1, 4, 16);
        p0 += __shfl_xor(p0, 2, 16); p1 += __shfl_xor(p1, 2, 16);
        p0 += __shfl_xor(p0, 1, 16); p1 += __shfl_xor(p1, 1, 16);
        if (t == 0) {
            float s0 = 1.f / (1.f + expf(-(p0 + bb)));
            float s1 = 1.f / (1.f + expf(-(p1 + bb)));
            __builtin_nontemporal_store(s0, &out[e0.y]);   // NT: keep L2 for P (R14 lesson)
            __builtin_nontemporal_store(s1, &out[e1.y]);
        }
    }
    if (j < end) {
        uint2 e0 = epk[j];
        uint2 pv = P8[(size_t)e0.x * 16 + t];
        float pf[8];
        f8x8_dec(pv, pf);
        float p0 = 0.f;
#pragma unroll
        for (int i = 0; i < 8; i++)
            p0 += fmaxf(pf[i] + qf[i], 0.f) * w[i];
        p0 += __shfl_xor(p0, 8, 16);
        p0 += __shfl_xor(p0, 4, 16);
        p0 += __shfl_xor(p0, 2, 16);
        p0 += __shfl_xor(p0, 1, 16);
        if (t == 0) {
            float s0 = 1.f / (1.f + expf(-(p0 + bb)));
            __builtin_nontemporal_store(s0, &out[e0.y]);
        }
    }
}

extern "C" void kernel_launch(void* const* d_in, const int* in_sizes, int n_in,
                              void* d_out, int out_size, void* d_ws, size_t ws_size,
                              hipStream_t stream) {
    const float* nf   = (const float*)d_in[0];
    const int*   ei   = (const int*)d_in[1];
    const float* ew1  = (const float*)d_in[2];
    const float* eb1  = (const float*)d_in[3];
    const float* ew2  = (const float*)d_in[4];
    const float* eb2  = (const float*)d_in[5];
    const float* cw1  = (const float*)d_in[6];
    const float* cb1  = (const float*)d_in[7];
    const float* cw2  = (const float*)d_in[8];
    const float* cb2  = (const float*)d_in[9];
    const float* cw3  = (const float*)d_in[10];
    const float* cb3  = (const float*)d_in[11];
    const float* clw1 = (const float*)d_in[12];
    const float* clb1 = (const float*)d_in[13];
    const float* clw2 = (const float*)d_in[14];
    const float* clb2 = (const float*)d_in[15];
    float* out = (float*)d_out;

    const int FD = 256;
    const int N = in_sizes[0] / FD;
    const int E = in_sizes[1] / 2;
    const int NBUCK = (N + 127) >> BSH;
    const int PBLK = 256;
    const int chunk = (E + PBLK - 1) / PBLK;

    size_t Np = ((size_t)N + 256) & ~(size_t)255;
    char* w = (char*)d_ws;
    float* dis     = (float*)w;            w += Np * 4;
    int*   tot     = (int*)w;              w += MAXBUCK * 4;   // memset region
    int*   gcur    = (int*)w;              w += MAXBUCK * 4;
    int*   base    = (int*)w;              w += (MAXBUCK + 4) * 4;
    int*   hist    = (int*)w;              w += (size_t)PBLK * MAXBUCK * 4;
    int*   row_ptr = (int*)w;              w += Np * 4;
    uint2* stag    = (uint2*)w;            w += (size_t)E * 8;
    uint2* epk     = (uint2*)w;            w += (size_t)E * 8;
    int*   col     = (int*)w;              w += (((size_t)E * 4) + 255) & ~(size_t)255;
    unsigned short* bufA = (unsigned short*)w;  w += (size_t)N * HDIM * 2;
    unsigned short* bufB = (unsigned short*)w;  w += (size_t)N * HDIM * 2;
    unsigned short* bufC = (unsigned short*)w;  w += (size_t)N * HDIM * 2;
    unsigned char*  f8X  = (unsigned char*)w;   w += ((size_t)N * HDIM + 255) & ~(size_t)255;  // 2 halves of N*64B
    unsigned char*  f8P  = (unsigned char*)w;   w += ((size_t)N * HDIM + 255) & ~(size_t)255;
    unsigned char*  f8Q  = (unsigned char*)w;   w += ((size_t)N * HDIM + 255) & ~(size_t)255;
    unsigned short* wtE1 = (unsigned short*)w;  w += 256 * HDIM * 2;
    unsigned short* wtE2 = (unsigned short*)w;  w += 128 * HDIM * 2;
    unsigned short* wtC1 = (unsigned short*)w;  w += 128 * HDIM * 2;
    unsigned short* wtC2 = (unsigned short*)w;  w += 128 * HDIM * 2;
    unsigned short* wtC3 = (unsigned short*)w;  w += 128 * HDIM * 2;
    unsigned short* wtT  = (unsigned short*)w;  w += 128 * HDIM * 2;
    unsigned short* wtB  = (unsigned short*)w;  w += 128 * HDIM * 2;

    unsigned char* f8Xh0 = f8X;
    unsigned char* f8Xh1 = f8X + (size_t)N * 64;

    int gemm_grid = (N + 63) / 64;
    int ag = (N + 3) / 4;

    // ---- weight prep ----
    WAll wa;
    wa.w[0] = { ew1,               wtE1, 256 };
    wa.w[1] = { ew2,               wtE2, 128 };
    wa.w[2] = { cw1,               wtC1, 128 };
    wa.w[3] = { cw2,               wtC2, 128 };
    wa.w[4] = { cw3,               wtC3, 128 };
    wa.w[5] = { clw1,              wtT,  128 };
    wa.w[6] = { clw1 + 128 * HDIM, wtB,  128 };
    k_prep_w<<<dim3(128, 7), 256, 0, stream>>>(wa);

    // ---- CSR build (bucketed; col + epk grouped by dst node) ----
    hipMemsetAsync(tot, 0, MAXBUCK * sizeof(int), stream);
    k_hist<<<PBLK, 256, 0, stream>>>(ei + E, tot, hist, E, chunk, NBUCK);
    k_scan_buckets<<<1, 256, 0, stream>>>(tot, gcur, base, NBUCK);
    k_partition<<<PBLK, 256, 0, stream>>>(ei, ei + E, hist, gcur, stag, E, chunk, NBUCK);
    k_bucket_csr<<<NBUCK, 256, 0, stream>>>(base, stag, row_ptr, col, epk, dis, N, NBUCK);

    // ---- encoder (bf16) ----
    k_gemm_nf<<<gemm_grid, 256, 0, stream>>>(nf, wtE1, eb1, bufA, N, 1);
    k_gemm_b<<<gemm_grid, 256, 0, stream>>>(bufA, wtE2, eb2, nullptr, bufB, N, 0, 0);  // x0

    // ---- conv1: y = dis*(x0@W) as split fp8; per-half aggregate -> bf16 ----
    k_gemm_b<<<gemm_grid, 256, 0, stream>>>(bufB, wtC1, nullptr, dis, f8X, N, 0, 2);
    k_aggregate_f8h<<<ag, 256, 0, stream>>>(row_ptr, col, dis, (const uint2*)f8Xh0, cb1,      bufC,      N, 1);
    k_aggregate_f8h<<<ag, 256, 0, stream>>>(row_ptr, col, dis, (const uint2*)f8Xh1, cb1 + 64, bufC + 64, N, 1);
    // ---- conv2 ----
    k_gemm_b<<<gemm_grid, 256, 0, stream>>>(bufC, wtC2, nullptr, dis, f8X, N, 0, 2);
    k_aggregate_f8h<<<ag, 256, 0, stream>>>(row_ptr, col, dis, (const uint2*)f8Xh0, cb2,      bufA,      N, 1);
    k_aggregate_f8h<<<ag, 256, 0, stream>>>(row_ptr, col, dis, (const uint2*)f8Xh1, cb2 + 64, bufA + 64, N, 1);
    // ---- conv3 (no relu) ----
    k_gemm_b<<<gemm_grid, 256, 0, stream>>>(bufA, wtC3, nullptr, dis, f8X, N, 0, 2);
    k_aggregate_f8h<<<ag, 256, 0, stream>>>(row_ptr, col, dis, (const uint2*)f8Xh0, cb3,      bufB,      N, 0);
    k_aggregate_f8h<<<ag, 256, 0, stream>>>(row_ptr, col, dis, (const uint2*)f8Xh1, cb3 + 64, bufB + 64, N, 0); // x3

    // ---- edge classifier: P = x3@W1_top + b1 (fp8 flat), Q = x3@W1_bot (fp8 flat) ----
    k_gemm_b<<<gemm_grid, 256, 0, stream>>>(bufB, wtT, clb1, nullptr, f8P, N, 0, 1);
    k_gemm_b<<<gemm_grid, 256, 0, stream>>>(bufB, wtB, nullptr, nullptr, f8Q, N, 0, 1);

    // ---- scorer: wave per dst node (Q streamed once per node, P random, NT out) ----
    k_edge_score_csr<<<ag, 256, 0, stream>>>(row_ptr, epk, (const uint2*)f8P, (const uint2*)f8Q,
                                             clw2, clb2, out, N);
}

// Round 16
// 457.516 us; speedup vs baseline: 1.0890x; 1.0890x over previous
//
#include <hip/hip_runtime.h>
#include <math.h>

#define HDIM 128
#define BSH 7                 // bucket = dst >> 7 (128 nodes per bucket)
#define MAXBUCK 512

typedef __attribute__((ext_vector_type(8))) short    bf16x8;
typedef __attribute__((ext_vector_type(4))) float    f32x4;
typedef __attribute__((ext_vector_type(2))) float    f32x2;
typedef __attribute__((ext_vector_type(8))) unsigned short u16x8;
typedef __attribute__((ext_vector_type(4))) unsigned short u16x4;

__device__ __forceinline__ float bf2f(unsigned short u) {
    union { unsigned int i; float f; } c; c.i = ((unsigned int)u) << 16; return c.f;
}
__device__ __forceinline__ unsigned short f2bf(float f) {
    union { float f; unsigned int i; } c; c.f = f;
    unsigned int r = (c.i + 0x7fffu + ((c.i >> 16) & 1u)) >> 16;
    return (unsigned short)r;
}
// decode 8 fp8 (e4m3) packed in uint2 -> 8 floats
__device__ __forceinline__ void f8x8_dec(uint2 v, float* f) {
    f32x2 a = __builtin_amdgcn_cvt_pk_f32_fp8((int)v.x, false);
    f32x2 b = __builtin_amdgcn_cvt_pk_f32_fp8((int)v.x, true);
    f32x2 c = __builtin_amdgcn_cvt_pk_f32_fp8((int)v.y, false);
    f32x2 d = __builtin_amdgcn_cvt_pk_f32_fp8((int)v.y, true);
    f[0] = a.x; f[1] = a.y; f[2] = b.x; f[3] = b.y;
    f[4] = c.x; f[5] = c.y; f[6] = d.x; f[7] = d.y;
}

// ---------------- CSR stage 1: per-block bucket histograms ----------------
__global__ __launch_bounds__(256) void k_hist(
    const int* __restrict__ dst, int* __restrict__ tot,
    int* __restrict__ hist, int E, int chunk, int nbuck)
{
    __shared__ int h[MAXBUCK];
    for (int i = threadIdx.x; i < MAXBUCK; i += 256) h[i] = 0;
    __syncthreads();
    int beg = blockIdx.x * chunk;
    int fin = min(beg + chunk, E);
    for (int e = beg + threadIdx.x; e < fin; e += 256)
        atomicAdd(&h[dst[e] >> BSH], 1);
    __syncthreads();
    for (int k = threadIdx.x; k < nbuck; k += 256) {
        int v = h[k];
        hist[(size_t)blockIdx.x * nbuck + k] = v;
        if (v) atomicAdd(&tot[k], v);
    }
}

// ---------------- CSR stage 2: exclusive scan of bucket totals ----------------
__global__ __launch_bounds__(256) void k_scan_buckets(
    const int* __restrict__ tot, int* __restrict__ gcur, int* __restrict__ base, int nbuck)
{
    __shared__ int a[MAXBUCK], b[MAXBUCK];
    int t = threadIdx.x;
    for (int i = t; i < MAXBUCK; i += 256) a[i] = (i < nbuck) ? tot[i] : 0;
    __syncthreads();
    int* s1 = a; int* s2 = b;
    for (int off = 1; off < MAXBUCK; off <<= 1) {
        for (int i = t; i < MAXBUCK; i += 256)
            s2[i] = s1[i] + ((i >= off) ? s1[i - off] : 0);
        __syncthreads();
        int* tmp = s1; s1 = s2; s2 = tmp;
    }
    for (int i = t; i < nbuck; i += 256) {
        int e = (i == 0) ? 0 : s1[i - 1];
        gcur[i] = e;
        base[i] = e;
    }
    if (t == 0) base[nbuck] = s1[nbuck - 1];
}

// ---------------- CSR stage 3: partition edges into bucket segments ----------------
// staging entry: { src | (dst<<16), edge_id }  (N < 65536)
__global__ __launch_bounds__(256) void k_partition(
    const int* __restrict__ src, const int* __restrict__ dst,
    const int* __restrict__ hist, int* __restrict__ gcur,
    uint2* __restrict__ stag, int E, int chunk, int nbuck)
{
    __shared__ int h[MAXBUCK];
    int t = threadIdx.x;
    for (int k = t; k < nbuck; k += 256) {
        int v = hist[(size_t)blockIdx.x * nbuck + k];
        h[k] = v ? atomicAdd(&gcur[k], v) : 0;
    }
    __syncthreads();
    int beg = blockIdx.x * chunk;
    int fin = min(beg + chunk, E);
    for (int e = beg + t; e < fin; e += 256) {
        unsigned int d = (unsigned int)dst[e];
        unsigned int s = (unsigned int)src[e];
        int pos = atomicAdd(&h[d >> BSH], 1);
        stag[pos] = make_uint2(s | (d << 16), (unsigned int)e);
    }
}

// ---------------- CSR stage 4: per-bucket counts + row_ptr + col/epk scatter + dis ----------------
// col[pos] = src (4B, for aggregates); epk[pos] = { src, edge_id } (for scorer).
__global__ __launch_bounds__(256) void k_bucket_csr(
    const int* __restrict__ base, const uint2* __restrict__ stag,
    int* __restrict__ row_ptr, int* __restrict__ col, uint2* __restrict__ epk,
    float* __restrict__ dis, int n, int nbuck)
{
    __shared__ int cl[128], sa[128], sb[128], cur[128];
    int k = blockIdx.x;
    int n0 = k << BSH;
    int t = threadIdx.x;
    if (t < 128) cl[t] = 0;
    __syncthreads();
    int b0 = base[k];
    int m = base[k + 1] - b0;
    const uint2* seg = stag + b0;
    for (int i = t; i < m; i += 256) atomicAdd(&cl[(seg[i].x >> 16) & 127], 1);
    __syncthreads();
    int cv = 0;
    if (t < 128) { cv = cl[t]; sa[t] = cv; }
    __syncthreads();
    int* s1 = sa; int* s2 = sb;
    for (int off = 1; off < 128; off <<= 1) {
        if (t < 128) s2[t] = s1[t] + ((t >= off) ? s1[t - off] : 0);
        __syncthreads();
        int* tmp = s1; s1 = s2; s2 = tmp;
    }
    if (t < 128) {
        int node = n0 + t;
        if (node < n) {
            int rpv = b0 + s1[t] - cv;
            row_ptr[node] = rpv;
            cur[t] = rpv;
            dis[node] = rsqrtf(1.0f + (float)cv);
        }
    }
    if (k == 0 && t == 0) row_ptr[n] = base[nbuck];
    __syncthreads();
    for (int i = t; i < m; i += 256) {
        uint2 e = seg[i];
        int pos = atomicAdd(&cur[(e.x >> 16) & 127], 1);
        int s = (int)(e.x & 0xffffu);
        col[pos] = s;
        epk[pos] = make_uint2((unsigned int)s, e.y);
    }
}

// ---------------- weight prep: fp32 W[KxH] -> bf16 W^T[HxK] ----------------
struct WEnt { const float* src; unsigned short* dst; int K; };
struct WAll { WEnt w[7]; };

__global__ __launch_bounds__(256) void k_prep_w(WAll all) {
    WEnt e = all.w[blockIdx.y];
    int i = blockIdx.x * 256 + threadIdx.x;
    if (i >= e.K * HDIM) return;
    int k = i >> 7, c = i & 127;
    e.dst[(size_t)c * e.K + k] = f2bf(e.src[i]);
}

// ---------------- MFMA GEMM (bf16 A), K=128; Wt staged in LDS (fragment order) ----------------
__global__ __launch_bounds__(256) void k_gemm_b(
    const unsigned short* __restrict__ X, const unsigned short* __restrict__ Wt,
    const float* __restrict__ bias, const float* __restrict__ scale,
    void* __restrict__ C, int M, int relu_out, int out_fp8)
{
    __shared__ unsigned short sW[128 * 128];   // 32 KB
    const int t = threadIdx.x;
#pragma unroll
    for (int i = 0; i < 8; i++) {
        int c = t + i * 256;                 // 16-B chunk 0..2047 (row-major source)
        int row = c >> 4, o = c & 15;        // row 0..127, o = k-octet 0..15
        int mt = row >> 4, r = row & 15, kc = o >> 2, q = o & 3;
        int lidx = (mt * 4 + kc) * 64 + q * 16 + r;
        *(uint4*)(sW + (size_t)lidx * 8) = *(const uint4*)(Wt + (size_t)c * 8);
    }
    __syncthreads();
    int wave = t >> 6, lane = t & 63;
    int quad = lane >> 4, r = lane & 15;
    int row0 = blockIdx.x * 64 + wave * 16;
    if (row0 >= M) return;                   // M % 16 == 0: whole waves only
    const unsigned short* xp = X + (size_t)(row0 + r) * 128 + quad * 8;
    f32x4 acc[8];
#pragma unroll
    for (int mt = 0; mt < 8; mt++) acc[mt] = (f32x4){0.f, 0.f, 0.f, 0.f};
#pragma unroll
    for (int kc = 0; kc < 4; kc++) {
        bf16x8 xf = *(const bf16x8*)(xp + kc * 32);
#pragma unroll
        for (int mt = 0; mt < 8; mt++) {
            bf16x8 wf = *(const bf16x8*)(sW + ((size_t)((mt * 4 + kc) * 64 + lane)) * 8);
            acc[mt] = __builtin_amdgcn_mfma_f32_16x16x32_bf16(wf, xf, acc[mt], 0, 0, 0);
        }
    }
    float sc = scale ? scale[row0 + r] : 1.f;
    if (out_fp8) {
        unsigned char* cp = (unsigned char*)C + (size_t)(row0 + r) * HDIM + quad * 4;
#pragma unroll
        for (int mt = 0; mt < 8; mt++) {
            float v[4];
#pragma unroll
            for (int j = 0; j < 4; j++) {
                float x = acc[mt][j];
                if (bias) x += bias[mt * 16 + quad * 4 + j];
                if (relu_out) x = fmaxf(x, 0.f);
                v[j] = x * sc;
            }
            int wd = 0;
            wd = __builtin_amdgcn_cvt_pk_fp8_f32(v[0], v[1], wd, false);
            wd = __builtin_amdgcn_cvt_pk_fp8_f32(v[2], v[3], wd, true);
            *(unsigned int*)(cp + mt * 16) = (unsigned int)wd;
        }
    } else {
        unsigned short* cp = (unsigned short*)C + (size_t)(row0 + r) * HDIM + quad * 4;
#pragma unroll
        for (int mt = 0; mt < 8; mt++) {
            u16x4 o;
#pragma unroll
            for (int j = 0; j < 4; j++) {
                float v = acc[mt][j];
                if (bias) v += bias[mt * 16 + quad * 4 + j];
                if (relu_out) v = fmaxf(v, 0.f);
                o[j] = f2bf(v * sc);
            }
            *(u16x4*)(cp + mt * 16) = o;
        }
    }
}

// ---------------- MFMA GEMM (fp32 A = node_features), K=256; Wt staged in LDS ----------------
__global__ __launch_bounds__(256) void k_gemm_nf(
    const float* __restrict__ X, const unsigned short* __restrict__ Wt,
    const float* __restrict__ bias, unsigned short* __restrict__ C,
    int M, int relu_out)
{
    const int K = 256;
    __shared__ unsigned short sW[128 * 256];   // 64 KB
    const int t = threadIdx.x;
#pragma unroll
    for (int i = 0; i < 16; i++) {
        int c = t + i * 256;                 // 16-B chunk 0..4095
        int row = c >> 5, o = c & 31;        // row 0..127, o = k-octet 0..31
        int mt = row >> 4, r = row & 15, kc = o >> 2, q = o & 3;
        int lidx = (mt * 8 + kc) * 64 + q * 16 + r;
        *(uint4*)(sW + (size_t)lidx * 8) = *(const uint4*)(Wt + (size_t)c * 8);
    }
    __syncthreads();
    int wave = t >> 6, lane = t & 63;
    int quad = lane >> 4, r = lane & 15;
    int row0 = blockIdx.x * 64 + wave * 16;
    if (row0 >= M) return;
    const float* xp = X + (size_t)(row0 + r) * K + quad * 8;
    f32x4 acc[8];
#pragma unroll
    for (int mt = 0; mt < 8; mt++) acc[mt] = (f32x4){0.f, 0.f, 0.f, 0.f};
#pragma unroll 2
    for (int kc = 0; kc < 8; kc++) {
        float4 xa = *(const float4*)(xp + kc * 32);
        float4 xb = *(const float4*)(xp + kc * 32 + 4);
        bf16x8 xf;
        xf[0] = (short)f2bf(xa.x); xf[1] = (short)f2bf(xa.y);
        xf[2] = (short)f2bf(xa.z); xf[3] = (short)f2bf(xa.w);
        xf[4] = (short)f2bf(xb.x); xf[5] = (short)f2bf(xb.y);
        xf[6] = (short)f2bf(xb.z); xf[7] = (short)f2bf(xb.w);
#pragma unroll
        for (int mt = 0; mt < 8; mt++) {
            bf16x8 wf = *(const bf16x8*)(sW + ((size_t)((mt * 8 + kc) * 64 + lane)) * 8);
            acc[mt] = __builtin_amdgcn_mfma_f32_16x16x32_bf16(wf, xf, acc[mt], 0, 0, 0);
        }
    }
    unsigned short* cp = C + (size_t)(row0 + r) * HDIM + quad * 4;
#pragma unroll
    for (int mt = 0; mt < 8; mt++) {
        u16x4 o;
#pragma unroll
        for (int j = 0; j < 4; j++) {
            float v = acc[mt][j];
            if (bias) v += bias[mt * 16 + quad * 4 + j];
            if (relu_out) v = fmaxf(v, 0.f);
            o[j] = f2bf(v);
        }
        *(u16x4*)(cp + mt * 16) = o;
    }
}

// ---------------- aggregate (pre-scaled fp8 y-table, quad layout, 8-deep ILP, col index) ----------------
__global__ __launch_bounds__(256) void k_aggregate_f8(
    const int* __restrict__ row_ptr, const int* __restrict__ col,
    const float* __restrict__ dis, const uint2* __restrict__ y8,
    const float* __restrict__ bias, unsigned short* __restrict__ out, int n, int relu_out)
{
    int wid = (blockIdx.x * 256 + threadIdx.x) >> 6;
    if (wid >= n) return;
    int lane = threadIdx.x & 63;
    int q = lane >> 4, t = lane & 15;
    float acc[8];
    {
        uint2 sv = y8[(size_t)wid * 16 + t];        // self term y[i]
        float f[8]; f8x8_dec(sv, f);
#pragma unroll
        for (int i = 0; i < 8; i++) acc[i] = (q == 0) ? f[i] : 0.f;
    }
    int beg = row_ptr[wid], end = row_ptr[wid + 1];
    int j = beg + q;
    // 8 independent gathers in flight
    for (; j + 28 < end; j += 32) {
        int s[8];
        uint2 v[8];
#pragma unroll
        for (int u = 0; u < 8; u++) s[u] = col[j + u * 4];
#pragma unroll
        for (int u = 0; u < 8; u++) v[u] = y8[(size_t)s[u] * 16 + t];
#pragma unroll
        for (int u = 0; u < 8; u++) {
            float f[8]; f8x8_dec(v[u], f);
#pragma unroll
            for (int i = 0; i < 8; i++) acc[i] += f[i];
        }
    }
    for (; j + 12 < end; j += 16) {
        int s0 = col[j], s1 = col[j + 4], s2 = col[j + 8], s3 = col[j + 12];
        uint2 v0 = y8[(size_t)s0 * 16 + t];
        uint2 v1 = y8[(size_t)s1 * 16 + t];
        uint2 v2 = y8[(size_t)s2 * 16 + t];
        uint2 v3 = y8[(size_t)s3 * 16 + t];
        float f0[8], f1[8], f2[8], f3[8];
        f8x8_dec(v0, f0); f8x8_dec(v1, f1); f8x8_dec(v2, f2); f8x8_dec(v3, f3);
#pragma unroll
        for (int i = 0; i < 8; i++) acc[i] += (f0[i] + f1[i]) + (f2[i] + f3[i]);
    }
    for (; j < end; j += 4) {
        int s = col[j];
        uint2 v = y8[(size_t)s * 16 + t];
        float f[8]; f8x8_dec(v, f);
#pragma unroll
        for (int i = 0; i < 8; i++) acc[i] += f[i];
    }
#pragma unroll
    for (int i = 0; i < 8; i++) {
        acc[i] += __shfl_xor(acc[i], 16, 64);
        acc[i] += __shfl_xor(acc[i], 32, 64);
    }
    if (q == 0) {
        float di = dis[wid];
        u16x8 o;
#pragma unroll
        for (int i = 0; i < 8; i++) {
            float v = di * acc[i] + bias[t * 8 + i];
            if (relu_out) v = fmaxf(v, 0.f);
            o[i] = f2bf(v);
        }
        *(u16x8*)(out + (size_t)wid * HDIM + t * 8) = o;
    }
}

// ---------------- edge scorer: wave per dst node, Q loaded once, P random, NT out ----------------
__global__ __launch_bounds__(256) void k_edge_score_csr(
    const int* __restrict__ row_ptr, const uint2* __restrict__ epk,
    const uint2* __restrict__ P8, const uint2* __restrict__ Q8,
    const float* __restrict__ w2, const float* __restrict__ b2,
    float* __restrict__ out, int n)
{
    int wid = (blockIdx.x * 256 + threadIdx.x) >> 6;
    if (wid >= n) return;
    int lane = threadIdx.x & 63;
    int q = lane >> 4, t = lane & 15;
    float w[8];
#pragma unroll
    for (int j = 0; j < 8; j++) w[j] = w2[t * 8 + j];
    float bb = b2[0];
    float qf[8];
    {
        uint2 qv = Q8[(size_t)wid * 16 + t];  // sequential per node, shared by all 4 quads
        f8x8_dec(qv, qf);
    }
    int beg = row_ptr[wid], end = row_ptr[wid + 1];
    int j = beg + q;
    for (; j + 4 < end; j += 8) {
        uint2 e0 = epk[j], e1 = epk[j + 4];
        uint2 pv0 = P8[(size_t)e0.x * 16 + t];
        uint2 pv1 = P8[(size_t)e1.x * 16 + t];
        float pf0[8], pf1[8];
        f8x8_dec(pv0, pf0); f8x8_dec(pv1, pf1);
        float p0 = 0.f, p1 = 0.f;
#pragma unroll
        for (int i = 0; i < 8; i++) {
            p0 += fmaxf(pf0[i] + qf[i], 0.f) * w[i];
            p1 += fmaxf(pf1[i] + qf[i], 0.f) * w[i];
        }
        p0 += __shfl_xor(p0, 8, 16); p1 += __shfl_xor(p1, 8, 16);
        p0 += __shfl_xor(p0, 4, 16); p1 += __shfl_xor(p1, 4, 16);
        p0 += __shfl_xor(p0, 2, 16); p1 += __shfl_xor(p1, 2, 16);
        p0 += __shfl_xor(p0, 1, 16); p1 += __shfl_xor(p1, 1, 16);
        if (t == 0) {
            float s0 = 1.f / (1.f + expf(-(p0 + bb)));
            float s1 = 1.f / (1.f + expf(-(p1 + bb)));
            __builtin_nontemporal_store(s0, &out[e0.y]);   // NT: keep L2 for P (R14 lesson)
            __builtin_nontemporal_store(s1, &out[e1.y]);
        }
    }
    if (j < end) {
        uint2 e0 = epk[j];
        uint2 pv = P8[(size_t)e0.x * 16 + t];
        float pf[8];
        f8x8_dec(pv, pf);
        float p0 = 0.f;
#pragma unroll
        for (int i = 0; i < 8; i++)
            p0 += fmaxf(pf[i] + qf[i], 0.f) * w[i];
        p0 += __shfl_xor(p0, 8, 16);
        p0 += __shfl_xor(p0, 4, 16);
        p0 += __shfl_xor(p0, 2, 16);
        p0 += __shfl_xor(p0, 1, 16);
        if (t == 0) {
            float s0 = 1.f / (1.f + expf(-(p0 + bb)));
            __builtin_nontemporal_store(s0, &out[e0.y]);
        }
    }
}

extern "C" void kernel_launch(void* const* d_in, const int* in_sizes, int n_in,
                              void* d_out, int out_size, void* d_ws, size_t ws_size,
                              hipStream_t stream) {
    const float* nf   = (const float*)d_in[0];
    const int*   ei   = (const int*)d_in[1];
    const float* ew1  = (const float*)d_in[2];
    const float* eb1  = (const float*)d_in[3];
    const float* ew2  = (const float*)d_in[4];
    const float* eb2  = (const float*)d_in[5];
    const float* cw1  = (const float*)d_in[6];
    const float* cb1  = (const float*)d_in[7];
    const float* cw2  = (const float*)d_in[8];
    const float* cb2  = (const float*)d_in[9];
    const float* cw3  = (const float*)d_in[10];
    const float* cb3  = (const float*)d_in[11];
    const float* clw1 = (const float*)d_in[12];
    const float* clb1 = (const float*)d_in[13];
    const float* clw2 = (const float*)d_in[14];
    const float* clb2 = (const float*)d_in[15];
    float* out = (float*)d_out;

    const int FD = 256;
    const int N = in_sizes[0] / FD;
    const int E = in_sizes[1] / 2;
    const int NBUCK = (N + 127) >> BSH;
    const int PBLK = 256;
    const int chunk = (E + PBLK - 1) / PBLK;

    size_t Np = ((size_t)N + 256) & ~(size_t)255;
    char* w = (char*)d_ws;
    float* dis     = (float*)w;            w += Np * 4;
    int*   tot     = (int*)w;              w += MAXBUCK * 4;   // memset region
    int*   gcur    = (int*)w;              w += MAXBUCK * 4;
    int*   base    = (int*)w;              w += (MAXBUCK + 4) * 4;
    int*   hist    = (int*)w;              w += (size_t)PBLK * MAXBUCK * 4;
    int*   row_ptr = (int*)w;              w += Np * 4;
    uint2* stag    = (uint2*)w;            w += (size_t)E * 8;
    uint2* epk     = (uint2*)w;            w += (size_t)E * 8;
    int*   col     = (int*)w;              w += (((size_t)E * 4) + 255) & ~(size_t)255;
    unsigned short* bufA = (unsigned short*)w;  w += (size_t)N * HDIM * 2;
    unsigned short* bufB = (unsigned short*)w;  w += (size_t)N * HDIM * 2;
    unsigned short* bufC = (unsigned short*)w;  w += (size_t)N * HDIM * 2;
    unsigned char*  f8X  = (unsigned char*)w;   w += ((size_t)N * HDIM + 255) & ~(size_t)255;
    unsigned char*  f8P  = (unsigned char*)w;   w += ((size_t)N * HDIM + 255) & ~(size_t)255;
    unsigned char*  f8Q  = (unsigned char*)w;   w += ((size_t)N * HDIM + 255) & ~(size_t)255;
    unsigned short* wtE1 = (unsigned short*)w;  w += 256 * HDIM * 2;
    unsigned short* wtE2 = (unsigned short*)w;  w += 128 * HDIM * 2;
    unsigned short* wtC1 = (unsigned short*)w;  w += 128 * HDIM * 2;
    unsigned short* wtC2 = (unsigned short*)w;  w += 128 * HDIM * 2;
    unsigned short* wtC3 = (unsigned short*)w;  w += 128 * HDIM * 2;
    unsigned short* wtT  = (unsigned short*)w;  w += 128 * HDIM * 2;
    unsigned short* wtB  = (unsigned short*)w;  w += 128 * HDIM * 2;

    int gemm_grid = (N + 63) / 64;
    int ag = (N + 3) / 4;

    // ---- weight prep ----
    WAll wa;
    wa.w[0] = { ew1,               wtE1, 256 };
    wa.w[1] = { ew2,               wtE2, 128 };
    wa.w[2] = { cw1,               wtC1, 128 };
    wa.w[3] = { cw2,               wtC2, 128 };
    wa.w[4] = { cw3,               wtC3, 128 };
    wa.w[5] = { clw1,              wtT,  128 };
    wa.w[6] = { clw1 + 128 * HDIM, wtB,  128 };
    k_prep_w<<<dim3(128, 7), 256, 0, stream>>>(wa);

    // ---- CSR build (bucketed; col + epk grouped by dst node) ----
    hipMemsetAsync(tot, 0, MAXBUCK * sizeof(int), stream);
    k_hist<<<PBLK, 256, 0, stream>>>(ei + E, tot, hist, E, chunk, NBUCK);
    k_scan_buckets<<<1, 256, 0, stream>>>(tot, gcur, base, NBUCK);
    k_partition<<<PBLK, 256, 0, stream>>>(ei, ei + E, hist, gcur, stag, E, chunk, NBUCK);
    k_bucket_csr<<<NBUCK, 256, 0, stream>>>(base, stag, row_ptr, col, epk, dis, N, NBUCK);

    // ---- encoder (bf16) ----
    k_gemm_nf<<<gemm_grid, 256, 0, stream>>>(nf, wtE1, eb1, bufA, N, 1);
    k_gemm_b<<<gemm_grid, 256, 0, stream>>>(bufA, wtE2, eb2, nullptr, bufB, N, 0, 0);  // x0

    // ---- conv1: y = dis*(x0@W) as fp8; aggregate -> bf16 ----
    k_gemm_b<<<gemm_grid, 256, 0, stream>>>(bufB, wtC1, nullptr, dis, f8X, N, 0, 1);
    k_aggregate_f8<<<ag, 256, 0, stream>>>(row_ptr, col, dis, (const uint2*)f8X, cb1, bufC, N, 1);
    // ---- conv2 ----
    k_gemm_b<<<gemm_grid, 256, 0, stream>>>(bufC, wtC2, nullptr, dis, f8X, N, 0, 1);
    k_aggregate_f8<<<ag, 256, 0, stream>>>(row_ptr, col, dis, (const uint2*)f8X, cb2, bufA, N, 1);
    // ---- conv3 (no relu) ----
    k_gemm_b<<<gemm_grid, 256, 0, stream>>>(bufA, wtC3, nullptr, dis, f8X, N, 0, 1);
    k_aggregate_f8<<<ag, 256, 0, stream>>>(row_ptr, col, dis, (const uint2*)f8X, cb3, bufB, N, 0); // x3

    // ---- edge classifier: P = x3@W1_top + b1 (fp8), Q = x3@W1_bot (fp8) ----
    k_gemm_b<<<gemm_grid, 256, 0, stream>>>(bufB, wtT, clb1, nullptr, f8P, N, 0, 1);
    k_gemm_b<<<gemm_grid, 256, 0, stream>>>(bufB, wtB, nullptr, nullptr, f8Q, N, 0, 1);

    // ---- scorer: wave per dst node (Q streamed once per node, P random, NT out) ----
    k_edge_score_csr<<<ag, 256, 0, stream>>>(row_ptr, epk, (const uint2*)f8P, (const uint2*)f8Q,
                                             clw2, clb2, out, N);
}